// Round 14
// baseline (156.347 us; speedup 1.0000x reference)
//
#include <hip/hip_runtime.h>

typedef unsigned int u32;
typedef unsigned short u16;
typedef short short8 __attribute__((ext_vector_type(8)));
typedef float f32x4 __attribute__((ext_vector_type(4)));
typedef u32 u32x2 __attribute__((ext_vector_type(2)));
typedef u32 u32x4 __attribute__((ext_vector_type(4)));

#define DEV static __device__ __forceinline__

// ---------------- threefry2x32 (JAX-compatible, 20 rounds) ----------------
__host__ __device__ constexpr u32 rotl32(u32 x, int r){ return (x << r) | (x >> (32 - r)); }
struct TF2 { u32 a, b; };

__host__ __device__ constexpr TF2 threefry2x32(u32 k0, u32 k1, u32 x0, u32 x1){
  u32 ks0 = k0, ks1 = k1, ks2 = k0 ^ k1 ^ 0x1BD11BDAu;
  x0 += ks0; x1 += ks1;
  x0 += x1; x1 = rotl32(x1,13); x1 ^= x0;
  x0 += x1; x1 = rotl32(x1,15); x1 ^= x0;
  x0 += x1; x1 = rotl32(x1,26); x1 ^= x0;
  x0 += x1; x1 = rotl32(x1, 6); x1 ^= x0;
  x0 += ks1; x1 += ks2 + 1u;
  x0 += x1; x1 = rotl32(x1,17); x1 ^= x0;
  x0 += x1; x1 = rotl32(x1,29); x1 ^= x0;
  x0 += x1; x1 = rotl32(x1,16); x1 ^= x0;
  x0 += x1; x1 = rotl32(x1,24); x1 ^= x0;
  x0 += ks2; x1 += ks0 + 2u;
  x0 += x1; x1 = rotl32(x1,13); x1 ^= x0;
  x0 += x1; x1 = rotl32(x1,15); x1 ^= x0;
  x0 += x1; x1 = rotl32(x1,26); x1 ^= x0;
  x0 += x1; x1 = rotl32(x1, 6); x1 ^= x0;
  x0 += ks0; x1 += ks1 + 3u;
  x0 += x1; x1 = rotl32(x1,17); x1 ^= x0;
  x0 += x1; x1 = rotl32(x1,29); x1 ^= x0;
  x0 += x1; x1 = rotl32(x1,16); x1 ^= x0;
  x0 += x1; x1 = rotl32(x1,24); x1 ^= x0;
  x0 += ks1; x1 += ks2 + 4u;
  x0 += x1; x1 = rotl32(x1,13); x1 ^= x0;
  x0 += x1; x1 = rotl32(x1,15); x1 ^= x0;
  x0 += x1; x1 = rotl32(x1,26); x1 ^= x0;
  x0 += x1; x1 = rotl32(x1, 6); x1 ^= x0;
  x0 += ks2; x1 += ks0 + 5u;
  return TF2{x0, x1};
}

DEV u32 rndbits(u32 ka, u32 kb, u32 e){
  TF2 r = threefry2x32(ka, kb, 0u, e);
  return r.a ^ r.b;
}
DEV float u01(u32 bits){
  return __builtin_bit_cast(float, (bits >> 9) | 0x3f800000u) - 1.0f;
}

// ---------------- bf16 helpers ----------------
DEV u32 f2bf(float f){   // manual RNE (cold paths)
  u32 x = __builtin_bit_cast(u32, f);
  return (x + 0x7FFFu + ((x >> 16) & 1u)) >> 16;
}
DEV u32 pack2(float lo, float hi){   // hot path: single VOP3 instruction
  u32 r;
  asm("v_cvt_pk_bf16_f32 %0, %1, %2" : "=v"(r) : "v"(lo), "v"(hi));
  return r;
}
DEV float bf2f(u32 h){ return __builtin_bit_cast(float, h << 16); }

// ---------------- swizzled LDS offsets ----------------
DEV int tile32_off(int row, int k){
  return row*64 + ((((k >> 3) ^ ((row >> 1) & 3))) << 4) + ((k & 7) << 1);
}
DEV int act_off(int r, int c){
  return r*512 + ((((c >> 3) ^ (r & 7))) << 4) + ((c & 7) << 1);
}

DEV void gload16(const void* gp, void* lp){
  __builtin_amdgcn_global_load_lds(
      (const __attribute__((address_space(1))) void*)gp,
      (__attribute__((address_space(3))) void*)lp,
      16, 0, 0);
}

DEV f32x4 mfma16(short8 a, short8 b, f32x4 c){
  return __builtin_amdgcn_mfma_f32_16x16x32_bf16(a, b, c, 0, 0, 0);
}

// ======================= K_prep: fused wpre + coords + pecb =======================
// blocks 0..639   : weight pre-convert
// blocks 640..895 : coords via threefry
// blocks 896..900 : pe + combined bias cb
__global__ __launch_bounds__(256) void k_prep(
    const float* __restrict__ Wb2, const float* __restrict__ Wab,
    const float* __restrict__ Wan, const float* __restrict__ Wag,
    short8* __restrict__ wpre,
    const float* __restrict__ centers, float* __restrict__ coords,
    const float* __restrict__ gpv, const float* __restrict__ gpr,
    const float* __restrict__ Wp,  const float* __restrict__ bp,
    const float* __restrict__ Wap, const float* __restrict__ ba1,
    float* __restrict__ cb){
  __shared__ float pe[256];
  int b = blockIdx.x, t = threadIdx.x;
  if(b < 640){
    int gid = b*256 + t;            // 163840 total units
    int v = gid >> 15;
    int rem = gid & 32767;
    short8 pk;
    if(rem < 16384){
      const float* M = (rem < 8192) ? Wb2 : Wab;
      int loc = rem & 8191;
      int kk = loc >> 10;
      int c  = (loc >> 2) & 255;
      int ku = loc & 3;
      int k0 = kk*32 + ku*8;
      #pragma unroll
      for(int j = 0; j < 8; ++j)
        pk[j] = (short)f2bf(M[(v*256 + k0 + j)*256 + c]);
    } else {
      int loc = rem - 16384;
      int kk = loc >> 10;
      int w  = loc & 1023;
      int i  = w >> 8, tt = w & 255;
      int c  = i*64 + (tt >> 2);
      int k0 = kk*32 + (((tt & 3) ^ ((c >> 1) & 3)) << 3);
      #pragma unroll
      for(int j = 0; j < 8; ++j){
        int k = k0 + j;
        float val = (k < 256) ? Wan[(v*256 + k)*256 + c]
                              : Wag[(v*256 + (k - 256))*256 + c];
        pk[j] = (short)f2bf(val);
      }
    }
    wpre[gid] = pk;
  } else if(b < 896){
    int q = (b - 640)*256 + t;      // q = n*8 + k, 65536 total
    int n = q >> 3, k = q & 7;
    constexpr TF2 KD = threefry2x32(0u, 42u, 0u, 0u);
    constexpr TF2 KR = threefry2x32(0u, 42u, 0u, 1u);
    float d[3], uu[3];
    #pragma unroll
    for(int c = 0; c < 3; ++c){
      u32 e = (u32)(q*3 + c);
      float fd = u01(rndbits(KD.a, KD.b, e));
      float fr = u01(rndbits(KR.a, KR.b, e));
      float un = fmaxf(-0.99999994f, fd*2.0f + (-0.99999994f));
      d[c]  = 1.41421356f * erfinvf(un);
      uu[c] = fr;
    }
    float nr = sqrtf(d[0]*d[0] + d[1]*d[1] + d[2]*d[2]);
    #pragma unroll
    for(int c = 0; c < 3; ++c){
      float ctr = centers[n*3 + c];
      float val = ctr + (d[c]/nr) * (0.02f * powf(uu[c], 0.33333334f));
      coords[((k + 1)*8192 + n)*3 + c] = val;   // layout [s][n][3]
      if(k == 0) coords[n*3 + c] = ctr;
    }
  } else {
    int v = b - 896;
    float r0 = gpv[0]/gpr[0], r1 = gpv[1]/gpr[1];
    pe[t] = fmaxf(r0*Wp[t] + r1*Wp[256 + t] + bp[t], 0.f);
    __syncthreads();
    float s = ba1[v*256 + t];
    #pragma unroll 8
    for(int d = 0; d < 256; ++d) s += pe[d] * Wap[(v*256 + d)*256 + t];
    cb[v*256 + t] = s;
  }
}

// ======================= K2: enc GEMM (8192 x 1280 x 512) =======================
__global__ __launch_bounds__(256) void k_enc(
    const short8* __restrict__ wpre, const float* __restrict__ en,
    const float* __restrict__ eg, const float* __restrict__ cb,
    u16* __restrict__ enc){
  __shared__ __align__(16) char lds[32768];
  char* ach = lds;
  char* bch = lds + 16384;
  int bx0 = blockIdx.x;
  int bx = (bx0 & 7)*80 + (bx0 >> 3);       // XCD-grouped (640 = 8*80)
  int t = threadIdx.x;
  int v  = bx >> 7;
  int n0 = (bx & 127) * 64;
  int wv = t >> 6, lane = t & 63, lc = lane & 15, hi = lane >> 4;
  f32x4 acc[4][4];
  #pragma unroll
  for(int mt = 0; mt < 4; ++mt)
    #pragma unroll
    for(int nt = 0; nt < 4; ++nt) acc[mt][nt] = f32x4{0.f,0.f,0.f,0.f};
  int bsr = t >> 2, bq = t & 3;
  #pragma unroll
  for(int kk = 0; kk < 16; ++kk){
    __syncthreads();
    const short8* wsrc = wpre + (v*32768 + 16384 + kk*1024 + t);
    #pragma unroll
    for(int i = 0; i < 4; ++i) gload16(wsrc + i*256, ach + i*4096 + wv*1024);
    {
      const float* src = ((kk < 8) ? en : eg) + (n0 + bsr)*256 + (kk & 7)*32 + bq*8;
      f32x4 f0 = *(const f32x4*)(src);
      f32x4 f1 = *(const f32x4*)(src + 4);
      u32x4 w; w[0] = pack2(f0[0], f0[1]); w[1] = pack2(f0[2], f0[3]);
      w[2] = pack2(f1[0], f1[1]); w[3] = pack2(f1[2], f1[3]);
      *(u32x4*)(bch + tile32_off(bsr, bq*8)) = w;
    }
    asm volatile("s_waitcnt vmcnt(0)" ::: "memory");
    __syncthreads();
    short8 a[4], b[4];
    #pragma unroll
    for(int mt = 0; mt < 4; ++mt)
      a[mt] = *(const short8*)(ach + tile32_off(64*wv + 16*mt + lc, hi*8));
    #pragma unroll
    for(int nt = 0; nt < 4; ++nt)
      b[nt] = *(const short8*)(bch + tile32_off(16*nt + lc, hi*8));
    #pragma unroll
    for(int mt = 0; mt < 4; ++mt)
      #pragma unroll
      for(int nt = 0; nt < 4; ++nt)
        acc[mt][nt] = mfma16(a[mt], b[nt], acc[mt][nt]);
  }
  __syncthreads();
  #pragma unroll
  for(int mt = 0; mt < 4; ++mt){
    f32x4 cbv = *(const f32x4*)(cb + v*256 + 64*wv + 16*mt + 4*hi);
    #pragma unroll
    for(int nt = 0; nt < 4; ++nt){
      u32x2 pk;
      pk[0] = pack2(acc[mt][nt][0] + cbv[0], acc[mt][nt][1] + cbv[1]);
      pk[1] = pack2(acc[mt][nt][2] + cbv[2], acc[mt][nt][3] + cbv[3]);
      *(u32x2*)(lds + act_off(16*nt + lc, 64*wv + 16*mt + 4*hi)) = pk;
    }
  }
  __syncthreads();
  #pragma unroll
  for(int i = 0; i < 8; ++i){
    int L = i*256 + t; int r = L >> 5; int u = L & 31;
    u32x4 val = *(const u32x4*)(lds + act_off(r, u*8));
    *(u32x4*)(enc + (size_t)(v*8192 + n0 + r)*256 + u*8) = val;
  }
}

// ======================= K3: fused basis chain (R4/R11 structure + T5 setprio) =======================
__global__ __launch_bounds__(256) void k_main(
    const short8* __restrict__ wpre, const float* __restrict__ coords,
    const float* __restrict__ Wb1, const float* __restrict__ bb1,
    const float* __restrict__ bb2, const u16* __restrict__ enc,
    const float* __restrict__ Wa2, float* __restrict__ part){
  __shared__ __align__(16) char act[32768];
  __shared__ float red[64][4];
  int t = threadIdx.x;
  int bx0 = blockIdx.x;
  int xcd = bx0 & 7;
  int idx = bx0 >> 3;          // 0..719
  int grp = idx / 9;           // 0..79
  int s   = idx - grp*9;       // 0..8
  int g   = xcd*80 + grp;      // 0..639
  int v   = g >> 7;
  int n0  = (g & 127) * 64;
  int wv = t >> 6, lane = t & 63, lc = lane & 15, hi = lane >> 4;

  // ---- b-fragment LDS base registers ----
  int base0 = lc*512 + 16*(hi ^ (lc & 3));
  int ks = ((lc >> 2) & 1) * 64;
  const char* bE = act + (base0 + ks);   // even kk
  const char* bO = act + (base0 - ks);   // odd kk

  // ---- biases (f32) ----
  f32x4 bv1[4], bv2[4];
  #pragma unroll
  for(int mt = 0; mt < 4; ++mt){
    bv1[mt] = *(const f32x4*)(bb1 + v*256 + 64*wv + 16*mt + 4*hi);
    bv2[mt] = *(const f32x4*)(bb2 + v*256 + 64*wv + 16*mt + 4*hi);
  }

  // ---- h1 fragments (K: k0-2 Wb1/coord_hi, k3-5 coord_lo; bias via acc init) ----
  short8 a1f[4], b1f[4];
  short8 z8 = {};
  #pragma unroll
  for(int i = 0; i < 4; ++i){ a1f[i] = z8; b1f[i] = z8; }
  if(hi == 0){
    #pragma unroll
    for(int mt = 0; mt < 4; ++mt){
      int c = 64*wv + 16*mt + lc;
      float w0 = Wb1[v*768 + c], w1 = Wb1[v*768 + 256 + c], w2 = Wb1[v*768 + 512 + c];
      u32x4 q; q[0] = pack2(w0, w1); q[1] = pack2(w2, w0);
      q[2] = pack2(w1, w2); q[3] = 0u;
      a1f[mt] = __builtin_bit_cast(short8, q);
    }
    #pragma unroll
    for(int nt = 0; nt < 4; ++nt){
      const float* cp = coords + (size_t)(s*8192 + n0 + 16*nt + lc)*3;
      float x = cp[0], y = cp[1], z = cp[2];
      float xh = bf2f(f2bf(x)), yh = bf2f(f2bf(y)), zh = bf2f(f2bf(z));
      u32x4 q;
      q[0] = pack2(x, y);
      q[1] = pack2(z, x - xh);
      q[2] = pack2(y - yh, z - zh);
      q[3] = 0u;
      b1f[nt] = __builtin_bit_cast(short8, q);
    }
  }

  f32x4 acc[4][4];
  #pragma unroll
  for(int mt = 0; mt < 4; ++mt)
    #pragma unroll
    for(int nt = 0; nt < 4; ++nt) acc[mt][nt] = bv1[mt];   // h1 bias init

  // ---- h1 via MFMA ----
  #pragma unroll
  for(int mt = 0; mt < 4; ++mt)
    #pragma unroll
    for(int nt = 0; nt < 4; ++nt)
      acc[mt][nt] = mfma16(a1f[mt], b1f[nt], acc[mt][nt]);

  // ---- repack: relu + pack + store to act ----
  auto repack = [&](){
    #pragma unroll
    for(int mt = 0; mt < 4; ++mt)
      #pragma unroll
      for(int nt = 0; nt < 4; ++nt){
        f32x4 h = acc[mt][nt];
        u32x2 pk;
        pk[0] = pack2(fmaxf(h[0], 0.f), fmaxf(h[1], 0.f));
        pk[1] = pack2(fmaxf(h[2], 0.f), fmaxf(h[3], 0.f));
        *(u32x2*)(act + act_off(16*nt + lc, 64*wv + 16*mt + 4*hi)) = pk;
      }
  };
  repack();                  // h1
  #pragma unroll
  for(int mt = 0; mt < 4; ++mt)
    #pragma unroll
    for(int nt = 0; nt < 4; ++nt) acc[mt][nt] = bv2[mt];   // gemm0 bias init
  __syncthreads();

  // ---- GEMM over K=256 in 8 chunks, weights direct global->VGPR ----
  // T5: setprio(1) around the MFMA cluster — co-resident blocks are at
  // different phases, so the CU scheduler can favor MFMA-issuing waves.
  const char* wbytes = (const char*)wpre + (size_t)v*524288 + (size_t)((64*wv + lc)*64 + hi*16);
  auto gemm = [&](int gm){
    const char* pw = wbytes + gm*131072;
    short8 aw[2][4];
    #pragma unroll
    for(int mt = 0; mt < 4; ++mt) aw[0][mt] = *(const short8*)(pw + mt*1024);
    #pragma unroll
    for(int kk = 0; kk < 8; ++kk){
      if(kk < 7){
        #pragma unroll
        for(int mt = 0; mt < 4; ++mt)
          aw[(kk & 1) ^ 1][mt] = *(const short8*)(pw + (kk + 1)*16384 + mt*1024);
      }
      const char* bp = (kk & 1) ? bO : bE;
      short8 bfr[4];
      #pragma unroll
      for(int nt = 0; nt < 4; ++nt)
        bfr[nt] = *(const short8*)(bp + nt*8192 + kk*64);
      __builtin_amdgcn_s_setprio(1);
      #pragma unroll
      for(int mt = 0; mt < 4; ++mt)
        #pragma unroll
        for(int nt = 0; nt < 4; ++nt)
          acc[mt][nt] = mfma16(aw[kk & 1][mt], bfr[nt], acc[mt][nt]);
      __builtin_amdgcn_s_setprio(0);
    }
  };

  gemm(0);                   // h2 = bb2 + h1 @ Wb2^T (pre-act)
  __syncthreads();
  repack();                  // h2 relu+pack
  #pragma unroll
  for(int mt = 0; mt < 4; ++mt)
    #pragma unroll
    for(int nt = 0; nt < 4; ++nt) acc[mt][nt] = f32x4{0.f,0.f,0.f,0.f};
  __syncthreads();
  gemm(1);                   // basis
  __syncthreads();

  // ---- stage enc tile into act ----
  {
    const u16* encp = enc + (size_t)(v*8192 + n0)*256;
    #pragma unroll
    for(int i = 0; i < 8; ++i){
      int r = i*8 + (t >> 5); int u = t & 31;
      u32x4 val = *(const u32x4*)(encp + (size_t)r*256 + u*8);
      *(u32x4*)(act + act_off(r, u*8)) = val;
    }
  }
  __syncthreads();

  // ---- epilogue: a1 = relu(basis + enc); dot Wa2; reduce ----
  f32x4 w4[4];
  #pragma unroll
  for(int mt = 0; mt < 4; ++mt)
    w4[mt] = *(const f32x4*)(Wa2 + v*256 + 64*wv + 16*mt + 4*hi);
  #pragma unroll
  for(int nt = 0; nt < 4; ++nt){
    float p = 0.f;
    #pragma unroll
    for(int mt = 0; mt < 4; ++mt){
      u32x2 e2 = *(const u32x2*)(act + act_off(16*nt + lc, 64*wv + 16*mt + 4*hi));
      f32x4 h = acc[mt][nt];
      float a0 = fmaxf(h[0] + bf2f(e2[0] & 0xFFFFu), 0.f);
      float a1 = fmaxf(h[1] + bf2f(e2[0] >> 16),     0.f);
      float a2 = fmaxf(h[2] + bf2f(e2[1] & 0xFFFFu), 0.f);
      float a3 = fmaxf(h[3] + bf2f(e2[1] >> 16),     0.f);
      p += a0*w4[mt][0] + a1*w4[mt][1] + a2*w4[mt][2] + a3*w4[mt][3];
    }
    p += __shfl_xor(p, 16, 64);
    p += __shfl_xor(p, 32, 64);
    if(hi == 0) red[16*nt + lc][wv] = p;
  }
  __syncthreads();
  if(t < 64){
    float sum = red[t][0] + red[t][1] + red[t][2] + red[t][3];
    part[(v*9 + s)*8192 + n0 + t] = sum;
  }
}

// ======================= K4: final weighted average over s =======================
__global__ __launch_bounds__(256) void k_fin(
    const float* __restrict__ part, const float* __restrict__ ba2,
    float* __restrict__ out){
  int i = blockIdx.x*256 + threadIdx.x;   // 40960 = N*V
  if(i >= 40960) return;
  int n = i / 5, v = i - n*5;
  const float* p = part + v*73728 + n;    // [v][s][n]
  float sm = 0.f;
  #pragma unroll
  for(int s = 1; s < 9; ++s) sm += p[s*8192];
  out[i] = ba2[v] + 0.5f*p[0] + 0.0625f*sm;
}

// ======================= launch =======================
extern "C" void kernel_launch(void* const* d_in, const int* in_sizes, int n_in,
                              void* d_out, int out_size, void* d_ws, size_t ws_size,
                              hipStream_t stream){
  const float* centers = (const float*)d_in[0];
  const float* eg   = (const float*)d_in[1];
  const float* en   = (const float*)d_in[2];
  const float* gpv  = (const float*)d_in[3];
  const float* gpr  = (const float*)d_in[4];
  const float* Wb1  = (const float*)d_in[5];
  const float* bb1  = (const float*)d_in[6];
  const float* Wb2  = (const float*)d_in[7];
  const float* bb2  = (const float*)d_in[8];
  const float* Wp   = (const float*)d_in[9];
  const float* bp   = (const float*)d_in[10];
  const float* Wab  = (const float*)d_in[11];
  const float* Wan  = (const float*)d_in[12];
  const float* Wag  = (const float*)d_in[13];
  const float* Wap  = (const float*)d_in[14];
  const float* ba1  = (const float*)d_in[15];
  const float* Wa2  = (const float*)d_in[16];
  const float* ba2  = (const float*)d_in[17];
  float* out = (float*)d_out;
  char* ws = (char*)d_ws;

  short8* wpre  = (short8*)(ws);                 // 2,621,440 B
  float* coords = (float*) (ws + 2621440);       //   884,736 B
  float* cb     = (float*) (ws + 3506176);       //     5,120 B
  float* partb  = (float*) (ws + 3511296);       // 1,474,560 B
  u16*   enc    = (u16*)   (ws + 4985856);       // 20,971,520 B

  k_prep <<<901,  256, 0, stream>>>(Wb2, Wab, Wan, Wag, wpre,
                                    centers, coords,
                                    gpv, gpr, Wp, bp, Wap, ba1, cb);
  k_enc  <<<640,  256, 0, stream>>>(wpre, en, eg, cb, enc);
  k_main <<<5760, 256, 0, stream>>>(wpre, coords, Wb1, bb1, bb2, enc, Wa2, partb);
  k_fin  <<<160,  256, 0, stream>>>(partb, ba2, out);
}

// Round 15
// 154.308 us; speedup vs baseline: 1.0132x; 1.0132x over previous
//
#include <hip/hip_runtime.h>

typedef unsigned int u32;
typedef unsigned short u16;
typedef short short8 __attribute__((ext_vector_type(8)));
typedef float f32x4 __attribute__((ext_vector_type(4)));
typedef u32 u32x2 __attribute__((ext_vector_type(2)));
typedef u32 u32x4 __attribute__((ext_vector_type(4)));

#define DEV static __device__ __forceinline__

// ---------------- threefry2x32 (JAX-compatible, 20 rounds) ----------------
__host__ __device__ constexpr u32 rotl32(u32 x, int r){ return (x << r) | (x >> (32 - r)); }
struct TF2 { u32 a, b; };

__host__ __device__ constexpr TF2 threefry2x32(u32 k0, u32 k1, u32 x0, u32 x1){
  u32 ks0 = k0, ks1 = k1, ks2 = k0 ^ k1 ^ 0x1BD11BDAu;
  x0 += ks0; x1 += ks1;
  x0 += x1; x1 = rotl32(x1,13); x1 ^= x0;
  x0 += x1; x1 = rotl32(x1,15); x1 ^= x0;
  x0 += x1; x1 = rotl32(x1,26); x1 ^= x0;
  x0 += x1; x1 = rotl32(x1, 6); x1 ^= x0;
  x0 += ks1; x1 += ks2 + 1u;
  x0 += x1; x1 = rotl32(x1,17); x1 ^= x0;
  x0 += x1; x1 = rotl32(x1,29); x1 ^= x0;
  x0 += x1; x1 = rotl32(x1,16); x1 ^= x0;
  x0 += x1; x1 = rotl32(x1,24); x1 ^= x0;
  x0 += ks2; x1 += ks0 + 2u;
  x0 += x1; x1 = rotl32(x1,13); x1 ^= x0;
  x0 += x1; x1 = rotl32(x1,15); x1 ^= x0;
  x0 += x1; x1 = rotl32(x1,26); x1 ^= x0;
  x0 += x1; x1 = rotl32(x1, 6); x1 ^= x0;
  x0 += ks0; x1 += ks1 + 3u;
  x0 += x1; x1 = rotl32(x1,17); x1 ^= x0;
  x0 += x1; x1 = rotl32(x1,29); x1 ^= x0;
  x0 += x1; x1 = rotl32(x1,16); x1 ^= x0;
  x0 += x1; x1 = rotl32(x1,24); x1 ^= x0;
  x0 += ks1; x1 += ks2 + 4u;
  x0 += x1; x1 = rotl32(x1,13); x1 ^= x0;
  x0 += x1; x1 = rotl32(x1,15); x1 ^= x0;
  x0 += x1; x1 = rotl32(x1,26); x1 ^= x0;
  x0 += x1; x1 = rotl32(x1, 6); x1 ^= x0;
  x0 += ks2; x1 += ks0 + 5u;
  return TF2{x0, x1};
}

DEV u32 rndbits(u32 ka, u32 kb, u32 e){
  TF2 r = threefry2x32(ka, kb, 0u, e);
  return r.a ^ r.b;
}
DEV float u01(u32 bits){
  return __builtin_bit_cast(float, (bits >> 9) | 0x3f800000u) - 1.0f;
}

// ---------------- bf16 helpers ----------------
DEV u32 f2bf(float f){   // manual RNE (cold paths)
  u32 x = __builtin_bit_cast(u32, f);
  return (x + 0x7FFFu + ((x >> 16) & 1u)) >> 16;
}
DEV u32 pack2(float lo, float hi){   // hot path: single VOP3 instruction
  u32 r;
  asm("v_cvt_pk_bf16_f32 %0, %1, %2" : "=v"(r) : "v"(lo), "v"(hi));
  return r;
}
DEV float bf2f(u32 h){ return __builtin_bit_cast(float, h << 16); }

// ---------------- swizzled LDS offsets ----------------
DEV int tile32_off(int row, int k){
  return row*64 + ((((k >> 3) ^ ((row >> 1) & 3))) << 4) + ((k & 7) << 1);
}
DEV int act_off(int r, int c){
  return r*512 + ((((c >> 3) ^ (r & 7))) << 4) + ((c & 7) << 1);
}

DEV void gload16(const void* gp, void* lp){
  __builtin_amdgcn_global_load_lds(
      (const __attribute__((address_space(1))) void*)gp,
      (__attribute__((address_space(3))) void*)lp,
      16, 0, 0);
}

DEV f32x4 mfma16(short8 a, short8 b, f32x4 c){
  return __builtin_amdgcn_mfma_f32_16x16x32_bf16(a, b, c, 0, 0, 0);
}

// ======================= K_prep: fused wpre + coords + pecb =======================
// blocks 0..639   : weight pre-convert
// blocks 640..895 : coords via threefry
// blocks 896..900 : pe + combined bias cb
__global__ __launch_bounds__(256) void k_prep(
    const float* __restrict__ Wb2, const float* __restrict__ Wab,
    const float* __restrict__ Wan, const float* __restrict__ Wag,
    short8* __restrict__ wpre,
    const float* __restrict__ centers, float* __restrict__ coords,
    const float* __restrict__ gpv, const float* __restrict__ gpr,
    const float* __restrict__ Wp,  const float* __restrict__ bp,
    const float* __restrict__ Wap, const float* __restrict__ ba1,
    float* __restrict__ cb){
  __shared__ float pe[256];
  int b = blockIdx.x, t = threadIdx.x;
  if(b < 640){
    int gid = b*256 + t;            // 163840 total units
    int v = gid >> 15;
    int rem = gid & 32767;
    short8 pk;
    if(rem < 16384){
      const float* M = (rem < 8192) ? Wb2 : Wab;
      int loc = rem & 8191;
      int kk = loc >> 10;
      int c  = (loc >> 2) & 255;
      int ku = loc & 3;
      int k0 = kk*32 + ku*8;
      #pragma unroll
      for(int j = 0; j < 8; ++j)
        pk[j] = (short)f2bf(M[(v*256 + k0 + j)*256 + c]);
    } else {
      int loc = rem - 16384;
      int kk = loc >> 10;
      int w  = loc & 1023;
      int i  = w >> 8, tt = w & 255;
      int c  = i*64 + (tt >> 2);
      int k0 = kk*32 + (((tt & 3) ^ ((c >> 1) & 3)) << 3);
      #pragma unroll
      for(int j = 0; j < 8; ++j){
        int k = k0 + j;
        float val = (k < 256) ? Wan[(v*256 + k)*256 + c]
                              : Wag[(v*256 + (k - 256))*256 + c];
        pk[j] = (short)f2bf(val);
      }
    }
    wpre[gid] = pk;
  } else if(b < 896){
    int q = (b - 640)*256 + t;      // q = n*8 + k, 65536 total
    int n = q >> 3, k = q & 7;
    constexpr TF2 KD = threefry2x32(0u, 42u, 0u, 0u);
    constexpr TF2 KR = threefry2x32(0u, 42u, 0u, 1u);
    float d[3], uu[3];
    #pragma unroll
    for(int c = 0; c < 3; ++c){
      u32 e = (u32)(q*3 + c);
      float fd = u01(rndbits(KD.a, KD.b, e));
      float fr = u01(rndbits(KR.a, KR.b, e));
      float un = fmaxf(-0.99999994f, fd*2.0f + (-0.99999994f));
      d[c]  = 1.41421356f * erfinvf(un);
      uu[c] = fr;
    }
    float nr = sqrtf(d[0]*d[0] + d[1]*d[1] + d[2]*d[2]);
    #pragma unroll
    for(int c = 0; c < 3; ++c){
      float ctr = centers[n*3 + c];
      float val = ctr + (d[c]/nr) * (0.02f * powf(uu[c], 0.33333334f));
      coords[((k + 1)*8192 + n)*3 + c] = val;   // layout [s][n][3]
      if(k == 0) coords[n*3 + c] = ctr;
    }
  } else {
    int v = b - 896;
    float r0 = gpv[0]/gpr[0], r1 = gpv[1]/gpr[1];
    pe[t] = fmaxf(r0*Wp[t] + r1*Wp[256 + t] + bp[t], 0.f);
    __syncthreads();
    float s = ba1[v*256 + t];
    #pragma unroll 8
    for(int d = 0; d < 256; ++d) s += pe[d] * Wap[(v*256 + d)*256 + t];
    cb[v*256 + t] = s;
  }
}

// ======================= K2: enc GEMM (8192 x 1280 x 512) =======================
__global__ __launch_bounds__(256) void k_enc(
    const short8* __restrict__ wpre, const float* __restrict__ en,
    const float* __restrict__ eg, const float* __restrict__ cb,
    u16* __restrict__ enc){
  __shared__ __align__(16) char lds[32768];
  char* ach = lds;
  char* bch = lds + 16384;
  int bx0 = blockIdx.x;
  int bx = (bx0 & 7)*80 + (bx0 >> 3);       // XCD-grouped (640 = 8*80)
  int t = threadIdx.x;
  int v  = bx >> 7;
  int n0 = (bx & 127) * 64;
  int wv = t >> 6, lane = t & 63, lc = lane & 15, hi = lane >> 4;
  f32x4 acc[4][4];
  #pragma unroll
  for(int mt = 0; mt < 4; ++mt)
    #pragma unroll
    for(int nt = 0; nt < 4; ++nt) acc[mt][nt] = f32x4{0.f,0.f,0.f,0.f};
  int bsr = t >> 2, bq = t & 3;
  #pragma unroll
  for(int kk = 0; kk < 16; ++kk){
    __syncthreads();
    const short8* wsrc = wpre + (v*32768 + 16384 + kk*1024 + t);
    #pragma unroll
    for(int i = 0; i < 4; ++i) gload16(wsrc + i*256, ach + i*4096 + wv*1024);
    {
      const float* src = ((kk < 8) ? en : eg) + (n0 + bsr)*256 + (kk & 7)*32 + bq*8;
      f32x4 f0 = *(const f32x4*)(src);
      f32x4 f1 = *(const f32x4*)(src + 4);
      u32x4 w; w[0] = pack2(f0[0], f0[1]); w[1] = pack2(f0[2], f0[3]);
      w[2] = pack2(f1[0], f1[1]); w[3] = pack2(f1[2], f1[3]);
      *(u32x4*)(bch + tile32_off(bsr, bq*8)) = w;
    }
    asm volatile("s_waitcnt vmcnt(0)" ::: "memory");
    __syncthreads();
    short8 a[4], b[4];
    #pragma unroll
    for(int mt = 0; mt < 4; ++mt)
      a[mt] = *(const short8*)(ach + tile32_off(64*wv + 16*mt + lc, hi*8));
    #pragma unroll
    for(int nt = 0; nt < 4; ++nt)
      b[nt] = *(const short8*)(bch + tile32_off(16*nt + lc, hi*8));
    #pragma unroll
    for(int mt = 0; mt < 4; ++mt)
      #pragma unroll
      for(int nt = 0; nt < 4; ++nt)
        acc[mt][nt] = mfma16(a[mt], b[nt], acc[mt][nt]);
  }
  __syncthreads();
  #pragma unroll
  for(int mt = 0; mt < 4; ++mt){
    f32x4 cbv = *(const f32x4*)(cb + v*256 + 64*wv + 16*mt + 4*hi);
    #pragma unroll
    for(int nt = 0; nt < 4; ++nt){
      u32x2 pk;
      pk[0] = pack2(acc[mt][nt][0] + cbv[0], acc[mt][nt][1] + cbv[1]);
      pk[1] = pack2(acc[mt][nt][2] + cbv[2], acc[mt][nt][3] + cbv[3]);
      *(u32x2*)(lds + act_off(16*nt + lc, 64*wv + 16*mt + 4*hi)) = pk;
    }
  }
  __syncthreads();
  #pragma unroll
  for(int i = 0; i < 8; ++i){
    int L = i*256 + t; int r = L >> 5; int u = L & 31;
    u32x4 val = *(const u32x4*)(lds + act_off(r, u*8));
    *(u32x4*)(enc + (size_t)(v*8192 + n0 + r)*256 + u*8) = val;
  }
}

// ======================= K3: fused basis chain (locked optimum: R4/R11/R13) =======================
__global__ __launch_bounds__(256) void k_main(
    const short8* __restrict__ wpre, const float* __restrict__ coords,
    const float* __restrict__ Wb1, const float* __restrict__ bb1,
    const float* __restrict__ bb2, const u16* __restrict__ enc,
    const float* __restrict__ Wa2, float* __restrict__ part){
  __shared__ __align__(16) char act[32768];
  __shared__ float red[64][4];
  int t = threadIdx.x;
  int bx0 = blockIdx.x;
  int xcd = bx0 & 7;
  int idx = bx0 >> 3;          // 0..719
  int grp = idx / 9;           // 0..79
  int s   = idx - grp*9;       // 0..8
  int g   = xcd*80 + grp;      // 0..639
  int v   = g >> 7;
  int n0  = (g & 127) * 64;
  int wv = t >> 6, lane = t & 63, lc = lane & 15, hi = lane >> 4;

  // ---- b-fragment LDS base registers ----
  int base0 = lc*512 + 16*(hi ^ (lc & 3));
  int ks = ((lc >> 2) & 1) * 64;
  const char* bE = act + (base0 + ks);   // even kk
  const char* bO = act + (base0 - ks);   // odd kk

  // ---- biases (f32) ----
  f32x4 bv1[4], bv2[4];
  #pragma unroll
  for(int mt = 0; mt < 4; ++mt){
    bv1[mt] = *(const f32x4*)(bb1 + v*256 + 64*wv + 16*mt + 4*hi);
    bv2[mt] = *(const f32x4*)(bb2 + v*256 + 64*wv + 16*mt + 4*hi);
  }

  // ---- h1 fragments (K: k0-2 Wb1/coord_hi, k3-5 coord_lo; bias via acc init) ----
  short8 a1f[4], b1f[4];
  short8 z8 = {};
  #pragma unroll
  for(int i = 0; i < 4; ++i){ a1f[i] = z8; b1f[i] = z8; }
  if(hi == 0){
    #pragma unroll
    for(int mt = 0; mt < 4; ++mt){
      int c = 64*wv + 16*mt + lc;
      float w0 = Wb1[v*768 + c], w1 = Wb1[v*768 + 256 + c], w2 = Wb1[v*768 + 512 + c];
      u32x4 q; q[0] = pack2(w0, w1); q[1] = pack2(w2, w0);
      q[2] = pack2(w1, w2); q[3] = 0u;
      a1f[mt] = __builtin_bit_cast(short8, q);
    }
    #pragma unroll
    for(int nt = 0; nt < 4; ++nt){
      const float* cp = coords + (size_t)(s*8192 + n0 + 16*nt + lc)*3;
      float x = cp[0], y = cp[1], z = cp[2];
      float xh = bf2f(f2bf(x)), yh = bf2f(f2bf(y)), zh = bf2f(f2bf(z));
      u32x4 q;
      q[0] = pack2(x, y);
      q[1] = pack2(z, x - xh);
      q[2] = pack2(y - yh, z - zh);
      q[3] = 0u;
      b1f[nt] = __builtin_bit_cast(short8, q);
    }
  }

  f32x4 acc[4][4];
  #pragma unroll
  for(int mt = 0; mt < 4; ++mt)
    #pragma unroll
    for(int nt = 0; nt < 4; ++nt) acc[mt][nt] = bv1[mt];   // h1 bias init

  // ---- h1 via MFMA ----
  #pragma unroll
  for(int mt = 0; mt < 4; ++mt)
    #pragma unroll
    for(int nt = 0; nt < 4; ++nt)
      acc[mt][nt] = mfma16(a1f[mt], b1f[nt], acc[mt][nt]);

  // ---- repack: relu + pack + store to act ----
  auto repack = [&](){
    #pragma unroll
    for(int mt = 0; mt < 4; ++mt)
      #pragma unroll
      for(int nt = 0; nt < 4; ++nt){
        f32x4 h = acc[mt][nt];
        u32x2 pk;
        pk[0] = pack2(fmaxf(h[0], 0.f), fmaxf(h[1], 0.f));
        pk[1] = pack2(fmaxf(h[2], 0.f), fmaxf(h[3], 0.f));
        *(u32x2*)(act + act_off(16*nt + lc, 64*wv + 16*mt + 4*hi)) = pk;
      }
  };
  repack();                  // h1
  #pragma unroll
  for(int mt = 0; mt < 4; ++mt)
    #pragma unroll
    for(int nt = 0; nt < 4; ++nt) acc[mt][nt] = bv2[mt];   // gemm0 bias init
  __syncthreads();

  // ---- GEMM over K=256 in 8 chunks, weights direct global->VGPR ----
  const char* wbytes = (const char*)wpre + (size_t)v*524288 + (size_t)((64*wv + lc)*64 + hi*16);
  auto gemm = [&](int gm){
    const char* pw = wbytes + gm*131072;
    short8 aw[2][4];
    #pragma unroll
    for(int mt = 0; mt < 4; ++mt) aw[0][mt] = *(const short8*)(pw + mt*1024);
    #pragma unroll
    for(int kk = 0; kk < 8; ++kk){
      if(kk < 7){
        #pragma unroll
        for(int mt = 0; mt < 4; ++mt)
          aw[(kk & 1) ^ 1][mt] = *(const short8*)(pw + (kk + 1)*16384 + mt*1024);
      }
      const char* bp = (kk & 1) ? bO : bE;
      short8 bfr[4];
      #pragma unroll
      for(int nt = 0; nt < 4; ++nt)
        bfr[nt] = *(const short8*)(bp + nt*8192 + kk*64);
      #pragma unroll
      for(int mt = 0; mt < 4; ++mt)
        #pragma unroll
        for(int nt = 0; nt < 4; ++nt)
          acc[mt][nt] = mfma16(aw[kk & 1][mt], bfr[nt], acc[mt][nt]);
    }
  };

  gemm(0);                   // h2 = bb2 + h1 @ Wb2^T (pre-act)
  __syncthreads();
  repack();                  // h2 relu+pack
  #pragma unroll
  for(int mt = 0; mt < 4; ++mt)
    #pragma unroll
    for(int nt = 0; nt < 4; ++nt) acc[mt][nt] = f32x4{0.f,0.f,0.f,0.f};
  __syncthreads();
  gemm(1);                   // basis
  __syncthreads();

  // ---- stage enc tile into act ----
  {
    const u16* encp = enc + (size_t)(v*8192 + n0)*256;
    #pragma unroll
    for(int i = 0; i < 8; ++i){
      int r = i*8 + (t >> 5); int u = t & 31;
      u32x4 val = *(const u32x4*)(encp + (size_t)r*256 + u*8);
      *(u32x4*)(act + act_off(r, u*8)) = val;
    }
  }
  __syncthreads();

  // ---- epilogue: a1 = relu(basis + enc); dot Wa2; reduce ----
  f32x4 w4[4];
  #pragma unroll
  for(int mt = 0; mt < 4; ++mt)
    w4[mt] = *(const f32x4*)(Wa2 + v*256 + 64*wv + 16*mt + 4*hi);
  #pragma unroll
  for(int nt = 0; nt < 4; ++nt){
    float p = 0.f;
    #pragma unroll
    for(int mt = 0; mt < 4; ++mt){
      u32x2 e2 = *(const u32x2*)(act + act_off(16*nt + lc, 64*wv + 16*mt + 4*hi));
      f32x4 h = acc[mt][nt];
      float a0 = fmaxf(h[0] + bf2f(e2[0] & 0xFFFFu), 0.f);
      float a1 = fmaxf(h[1] + bf2f(e2[0] >> 16),     0.f);
      float a2 = fmaxf(h[2] + bf2f(e2[1] & 0xFFFFu), 0.f);
      float a3 = fmaxf(h[3] + bf2f(e2[1] >> 16),     0.f);
      p += a0*w4[mt][0] + a1*w4[mt][1] + a2*w4[mt][2] + a3*w4[mt][3];
    }
    p += __shfl_xor(p, 16, 64);
    p += __shfl_xor(p, 32, 64);
    if(hi == 0) red[16*nt + lc][wv] = p;
  }
  __syncthreads();
  if(t < 64){
    float sum = red[t][0] + red[t][1] + red[t][2] + red[t][3];
    part[(v*9 + s)*8192 + n0 + t] = sum;
  }
}

// ======================= K4: final weighted average over s =======================
__global__ __launch_bounds__(256) void k_fin(
    const float* __restrict__ part, const float* __restrict__ ba2,
    float* __restrict__ out){
  int i = blockIdx.x*256 + threadIdx.x;   // 40960 = N*V
  if(i >= 40960) return;
  int n = i / 5, v = i - n*5;
  const float* p = part + v*73728 + n;    // [v][s][n]
  float sm = 0.f;
  #pragma unroll
  for(int s = 1; s < 9; ++s) sm += p[s*8192];
  out[i] = ba2[v] + 0.5f*p[0] + 0.0625f*sm;
}

// ======================= launch =======================
extern "C" void kernel_launch(void* const* d_in, const int* in_sizes, int n_in,
                              void* d_out, int out_size, void* d_ws, size_t ws_size,
                              hipStream_t stream){
  const float* centers = (const float*)d_in[0];
  const float* eg   = (const float*)d_in[1];
  const float* en   = (const float*)d_in[2];
  const float* gpv  = (const float*)d_in[3];
  const float* gpr  = (const float*)d_in[4];
  const float* Wb1  = (const float*)d_in[5];
  const float* bb1  = (const float*)d_in[6];
  const float* Wb2  = (const float*)d_in[7];
  const float* bb2  = (const float*)d_in[8];
  const float* Wp   = (const float*)d_in[9];
  const float* bp   = (const float*)d_in[10];
  const float* Wab  = (const float*)d_in[11];
  const float* Wan  = (const float*)d_in[12];
  const float* Wag  = (const float*)d_in[13];
  const float* Wap  = (const float*)d_in[14];
  const float* ba1  = (const float*)d_in[15];
  const float* Wa2  = (const float*)d_in[16];
  const float* ba2  = (const float*)d_in[17];
  float* out = (float*)d_out;
  char* ws = (char*)d_ws;

  short8* wpre  = (short8*)(ws);                 // 2,621,440 B
  float* coords = (float*) (ws + 2621440);       //   884,736 B
  float* cb     = (float*) (ws + 3506176);       //     5,120 B
  float* partb  = (float*) (ws + 3511296);       // 1,474,560 B
  u16*   enc    = (u16*)   (ws + 4985856);       // 20,971,520 B

  k_prep <<<901,  256, 0, stream>>>(Wb2, Wab, Wan, Wag, wpre,
                                    centers, coords,
                                    gpv, gpr, Wp, bp, Wap, ba1, cb);
  k_enc  <<<640,  256, 0, stream>>>(wpre, en, eg, cb, enc);
  k_main <<<5760, 256, 0, stream>>>(wpre, coords, Wb1, bb1, bb2, enc, Wa2, partb);
  k_fin  <<<160,  256, 0, stream>>>(partb, ba2, out);
}